// Round 6
// baseline (116.048 us; speedup 1.0000x reference)
//
#include <hip/hip_runtime.h>
#include <stdint.h>

// inputs [B=64, T=256, D=1024] f32; tanh -> sequential dual-threshold
// integrate-and-fire scan over T per (b,d).
//
// Structure (R5, kept): intra-block T-pipeline. Only the 9-op v-chain is
// sequential; loads and tanh are not. Block = 4 waves over the SAME 64
// sequences; wave k owns timesteps [64k,64k+64). 4096 waves = 16/CU.
// v-state hops wave->wave via LDS acquire/release flag (intra-block only
// -> co-residency guaranteed, no deadlock).
//
// Round-6 deltas (one mechanism: shorten critical path / overlap store
// drain — R0/R3/R4/R5 proved MLP and TLP levers are null, leaving the
// lock-step phase structure as the remaining suspect):
//  1. loads issued BEFORE the flag-init barrier; raw s_barrier with
//     lgkmcnt-only wait (plain __syncthreads would drain vmcnt(0)).
//  2. stores no longer `nt`: nothing waits on them, and committing to L2
//     lets the write stream drain lazily instead of at HBM rate in-tail.
//  3. wk=3 (the tail wave, behind 3 handoffs) interleaves scan/store per
//     16-slice so its store burst overlaps its own scan VALU.
#define B_DIM 64
#define T_STEPS 256
#define D_DIM 1024
#define TPB 256
#define SEQ_PER_BLK 64          // one wave-width of sequences per block
#define TQ 64                   // timesteps per wave (T/4)

// XLA/Eigen f32 tanh rational approximation — bit-exact vs jnp.tanh
// (verified: absmax = 0.0). DO NOT change the FMA structure.
__device__ __forceinline__ float xla_tanhf(float x) {
    const float kClamp = 7.90531110763549805f;
    float xc = fminf(fmaxf(x, -kClamp), kClamp);
    float x2 = xc * xc;
    float p = __builtin_fmaf(x2, -2.76076847742355e-16f, 2.00018790482477e-13f);
    p = __builtin_fmaf(x2, p, -8.60467152213735e-11f);
    p = __builtin_fmaf(x2, p, 5.12229709037114e-08f);
    p = __builtin_fmaf(x2, p, 1.48572235717979e-05f);
    p = __builtin_fmaf(x2, p, 6.37261928875436e-04f);
    p = __builtin_fmaf(x2, p, 4.89352455891786e-03f);
    p = xc * p;
    float q = __builtin_fmaf(x2, 1.19825839466702e-06f, 1.18534705686654e-04f);
    q = __builtin_fmaf(x2, q, 2.26843463243900e-03f);
    q = __builtin_fmaf(x2, q, 4.89352518554385e-03f);
    float r = p / q;           // IEEE divide — required for bit-exactness
    return (fabsf(x) < 0.0004f) ? x : r;
}

// --- raw-asm building blocks ---------------------------------------------
// One load + advance voff by one timestep (D_DIM*4 = 4096 B). saddr form:
// addr = SGPR base + zext(voff); tensor is 64 MB so 32-bit offsets fit.
#define LD(i) "global_load_dword %" #i ", %16, %17\n\t" \
              "v_add_u32 %16, 0x1000, %16\n\t"

// Issue 16 loads into 16-reg slice B; compiler never sees them as memory
// ops -> no auto-waitcnt; vmcnt tracked manually.
#define ISSUE16(B) asm volatile( \
    LD(0) LD(1) LD(2) LD(3) LD(4) LD(5) LD(6) LD(7) \
    LD(8) LD(9) LD(10) LD(11) LD(12) LD(13) LD(14) LD(15) \
    : "=v"(B[0]), "=v"(B[1]), "=v"(B[2]), "=v"(B[3]), \
      "=v"(B[4]), "=v"(B[5]), "=v"(B[6]), "=v"(B[7]), \
      "=v"(B[8]), "=v"(B[9]), "=v"(B[10]), "=v"(B[11]), \
      "=v"(B[12]), "=v"(B[13]), "=v"(B[14]), "=v"(B[15]), \
      "+v"(voffi) \
    : "s"(inp_u) : "memory")

// Wait until <= CNT vmem ops outstanding; "+v" on the slice makes every
// use data-dependent on this wait. Only loads are in the queue during the
// tanh phase (all stores happen after), so vmcnt(0) at the tail is safe.
#define WAITBUF(B, CNT) asm volatile("s_waitcnt vmcnt(" CNT ")" \
    : "+v"(B[0]), "+v"(B[1]), "+v"(B[2]), "+v"(B[3]), \
      "+v"(B[4]), "+v"(B[5]), "+v"(B[6]), "+v"(B[7]), \
      "+v"(B[8]), "+v"(B[9]), "+v"(B[10]), "+v"(B[11]), \
      "+v"(B[12]), "+v"(B[13]), "+v"(B[14]), "+v"(B[15]) \
    :: "memory")

// Opaque keep-alive: pins the tanh results so the compiler cannot sink
// the tanh chains below the spin loop.
#define KEEP16(B) asm volatile("" \
    : "+v"(B[0]), "+v"(B[1]), "+v"(B[2]), "+v"(B[3]), \
      "+v"(B[4]), "+v"(B[5]), "+v"(B[6]), "+v"(B[7]), \
      "+v"(B[8]), "+v"(B[9]), "+v"(B[10]), "+v"(B[11]), \
      "+v"(B[12]), "+v"(B[13]), "+v"(B[14]), "+v"(B[15]))

#define TANH16(B) do { \
    _Pragma("unroll") \
    for (int u = 0; u < 16; ++u) B[u] = xla_tanhf(B[u]); \
    KEEP16(B); } while (0)

// Scan 16 steps in place: consumes tanh value B[u], leaves output in B[u].
// Bit-exact op order preserved (the *0.01 stays fused in the fma).
#define SCAN16(B) do { \
    _Pragma("unroll") \
    for (int u = 0; u < 16; ++u) { \
        float r = B[u]; \
        v = __builtin_fmaf(r, 0.01f, v); \
        float sp = (v >= 1.0f)  ? 1.0f : 0.0f; \
        float sn = (v <= -1.0f) ? 1.0f : 0.0f; \
        v = (v - sp) + sn; \
        B[u] = (sp - sn) * 100.0f; \
    } } while (0)

// 16 plain stores (commit to L2, drain lazily; nothing ever waits on
// vmcnt after these so retire latency is off the critical path).
// voffo is a true "+v" in-out operand and advances 16 timesteps.
#define STORE16(B) asm volatile( \
    "global_store_dword %0, %1, %17\n\t"  "v_add_u32 %0, 0x1000, %0\n\t" \
    "global_store_dword %0, %2, %17\n\t"  "v_add_u32 %0, 0x1000, %0\n\t" \
    "global_store_dword %0, %3, %17\n\t"  "v_add_u32 %0, 0x1000, %0\n\t" \
    "global_store_dword %0, %4, %17\n\t"  "v_add_u32 %0, 0x1000, %0\n\t" \
    "global_store_dword %0, %5, %17\n\t"  "v_add_u32 %0, 0x1000, %0\n\t" \
    "global_store_dword %0, %6, %17\n\t"  "v_add_u32 %0, 0x1000, %0\n\t" \
    "global_store_dword %0, %7, %17\n\t"  "v_add_u32 %0, 0x1000, %0\n\t" \
    "global_store_dword %0, %8, %17\n\t"  "v_add_u32 %0, 0x1000, %0\n\t" \
    "global_store_dword %0, %9, %17\n\t"  "v_add_u32 %0, 0x1000, %0\n\t" \
    "global_store_dword %0, %10, %17\n\t" "v_add_u32 %0, 0x1000, %0\n\t" \
    "global_store_dword %0, %11, %17\n\t" "v_add_u32 %0, 0x1000, %0\n\t" \
    "global_store_dword %0, %12, %17\n\t" "v_add_u32 %0, 0x1000, %0\n\t" \
    "global_store_dword %0, %13, %17\n\t" "v_add_u32 %0, 0x1000, %0\n\t" \
    "global_store_dword %0, %14, %17\n\t" "v_add_u32 %0, 0x1000, %0\n\t" \
    "global_store_dword %0, %15, %17\n\t" "v_add_u32 %0, 0x1000, %0\n\t" \
    "global_store_dword %0, %16, %17\n\t" "v_add_u32 %0, 0x1000, %0\n\t" \
    : "+v"(voffo) \
    : "v"(B[0]), "v"(B[1]), "v"(B[2]), "v"(B[3]), \
      "v"(B[4]), "v"(B[5]), "v"(B[6]), "v"(B[7]), \
      "v"(B[8]), "v"(B[9]), "v"(B[10]), "v"(B[11]), \
      "v"(B[12]), "v"(B[13]), "v"(B[14]), "v"(B[15]), "s"(outp_u) \
    : "memory")

__global__ __launch_bounds__(TPB)
void spike_scan_kernel(const float* __restrict__ in, float* __restrict__ out) {
    __shared__ float vstate[3][SEQ_PER_BLK];   // v handed stage k -> k+1
    __shared__ unsigned int flag[4];

    const int lane = threadIdx.x & 63;
    const int wk   = threadIdx.x >> 6;         // pipeline stage 0..3

    // Block handles 64 consecutive sequences; wave k handles their
    // timesteps [wk*64, wk*64+64). seq = blockIdx*64 + lane.
    const uint32_t sgrp  = (uint32_t)blockIdx.x << 6;
    const uint32_t b     = sgrp >> 10;               // batch index
    const uint32_t dbase = sgrp & (D_DIM - 1);       // d range base
    uint32_t voffi = b * (T_STEPS * D_DIM * 4u)
                   + (uint32_t)wk * (TQ * D_DIM * 4u)
                   + (dbase + (uint32_t)lane) * 4u;
    uint32_t voffo = voffi;
    const uint64_t inp_u  = (uint64_t)in;
    const uint64_t outp_u = (uint64_t)out;

    float rA[16], rB[16], rC[16], rD[16];      // this wave's 64 timesteps

    // 1) Issue all 64 loads FIRST (cap-throttled past 63 outstanding —
    // harmless); they stay in flight across the barrier below.
    ISSUE16(rA); ISSUE16(rB); ISSUE16(rC); ISSUE16(rD);

    // Flag init + raw barrier: lgkmcnt-only wait (LDS write visibility);
    // a plain __syncthreads() would emit vmcnt(0) and drain the pipeline.
    if (threadIdx.x < 4) flag[threadIdx.x] = 0u;
    asm volatile("s_waitcnt lgkmcnt(0)" ::: "memory");
    __builtin_amdgcn_s_barrier();

    // tanh each slice as it lands. All 4 waves in parallel.
    WAITBUF(rA, "48"); TANH16(rA);
    WAITBUF(rB, "32"); TANH16(rB);
    WAITBUF(rC, "16"); TANH16(rC);
    WAITBUF(rD, "0");  TANH16(rD);

    // --- serial section: only the 9-op v-chain ---
    float v = 0.0f;
    if (wk != 0) {
        while (__hip_atomic_load(&flag[wk - 1], __ATOMIC_ACQUIRE,
                                 __HIP_MEMORY_SCOPE_WORKGROUP) == 0u)
            __builtin_amdgcn_s_sleep(1);
        v = vstate[wk - 1][lane];
    }
    if (wk != 3) {
        // Handoff ASAP (release before stores), then drain stores.
        SCAN16(rA); SCAN16(rB); SCAN16(rC); SCAN16(rD);
        vstate[wk][lane] = v;
        __hip_atomic_store(&flag[wk], 1u, __ATOMIC_RELEASE,
                           __HIP_MEMORY_SCOPE_WORKGROUP);
        STORE16(rA); STORE16(rB); STORE16(rC); STORE16(rD);
    } else {
        // Tail wave: no handoff; overlap its store burst with its scans.
        SCAN16(rA); STORE16(rA);
        SCAN16(rB); STORE16(rB);
        SCAN16(rC); STORE16(rC);
        SCAN16(rD); STORE16(rD);
    }
}

extern "C" void kernel_launch(void* const* d_in, const int* in_sizes, int n_in,
                              void* d_out, int out_size, void* d_ws, size_t ws_size,
                              hipStream_t stream) {
    const float* in = (const float*)d_in[0];
    float* out = (float*)d_out;
    dim3 block(TPB);
    dim3 grid((B_DIM * D_DIM) / SEQ_PER_BLK);   // 1024 blocks = 4096 waves
    spike_scan_kernel<<<grid, block, 0, stream>>>(in, out);
}